// Round 9
// baseline (8135.652 us; speedup 1.0000x reference)
//
#include <hip/hip_runtime.h>
#include <hip/hip_bf16.h>

// Problem constants
#define BB 32     // batch
#define TT 512    // time
#define AA 512    // acoustic dim
#define EE 256    // emb dim
#define HH 320    // hidden
#define VV 8192   // vocab
#define KIN 768   // A+E
#define G4 1280   // 4*H

#define NBLK 8    // recurrence blocks (one sync group)
#define UPB 40    // hidden units per block
#define RTHR 640  // threads in stage_rec (10 waves)
#define GLP 161   // gates LDS row pad (161 % 32 == 1 => conflict-free)

typedef __bf16 bf16x8v __attribute__((ext_vector_type(8)));
typedef float f32x4 __attribute__((ext_vector_type(4)));

__device__ __forceinline__ float fsigm(float x) { return 1.f / (1.f + __expf(-x)); }
__device__ __forceinline__ float ftanh(float x) { return 2.f / (1.f + __expf(-2.f * x)) - 1.f; }
__device__ __forceinline__ unsigned short f2bf(float f) {
    __hip_bfloat16 h = __float2bfloat16(f);
    return *(unsigned short*)&h;
}

// ---------------- Stage A: X[r=t*B+b][j] = tanh(concat(a,e) . W_in[j,:] + b_in[j]) ----------------
__global__ __launch_bounds__(320) void stage_x(const float* __restrict__ ac,
                                               const int* __restrict__ tok,
                                               const float* __restrict__ emb,
                                               const float* __restrict__ Win,
                                               const float* __restrict__ bin,
                                               float* __restrict__ X) {
    __shared__ float xs[8][KIN];
    const int r0 = blockIdx.x * 8;
    const int tid = threadIdx.x;
    for (int rr = 0; rr < 8; ++rr) {
        const int r = r0 + rr;
        const int t = r >> 5;
        const int b = r & 31;
        const int tk = tok[b * TT + t];
        const float4* ac4  = (const float4*)(ac + ((size_t)b * TT + t) * AA);
        const float4* emb4 = (const float4*)(emb + (size_t)tk * EE);
        float4* xs4 = (float4*)&xs[rr][0];
        for (int k4 = tid; k4 < KIN / 4; k4 += 320) {
            float4 v;
            if (k4 < AA / 4) v = ac4[k4];
            else if (tk == 0) v = make_float4(0.f, 0.f, 0.f, 0.f);
            else v = emb4[k4 - AA / 4];
            xs4[k4] = v;
        }
    }
    __syncthreads();
    const int j = tid;
    float acc[8];
    const float bj = bin[j];
#pragma unroll
    for (int rr = 0; rr < 8; ++rr) acc[rr] = bj;
    const float4* w4 = (const float4*)(Win + (size_t)j * KIN);
#pragma unroll 4
    for (int k4 = 0; k4 < KIN / 4; ++k4) {
        const float4 wv = w4[k4];
#pragma unroll
        for (int rr = 0; rr < 8; ++rr) {
            const float4 xv = ((const float4*)&xs[rr][0])[k4];
            acc[rr] += wv.x * xv.x + wv.y * xv.y + wv.z * xv.z + wv.w * xv.w;
        }
    }
#pragma unroll
    for (int rr = 0; rr < 8; ++rr)
        X[(size_t)(r0 + rr) * HH + j] = tanhf(acc[rr]);
}

// ---------------- Stage B: Gp layout [t][p][q][ugrp(10)][b(32)][4] ----------------
__global__ __launch_bounds__(256) void stage_gin(const float* __restrict__ X,
                                                 const float* __restrict__ Wih,
                                                 const float* __restrict__ bih,
                                                 const float* __restrict__ bhh,
                                                 float* __restrict__ Gp) {
    __shared__ float xs[8][HH];
    const int r0 = blockIdx.x * 8;
    const int tid = threadIdx.x;
    {
        const float4* src = (const float4*)(X + (size_t)r0 * HH);
        float4* dst = (float4*)&xs[0][0];
        for (int k4 = tid; k4 < 8 * HH / 4; k4 += 256) dst[k4] = src[k4];
    }
    __syncthreads();
    const int t = r0 >> 5;
    const int b0 = r0 & 31;
    for (int p5 = 0; p5 < 5; ++p5) {
        const int j = tid + 256 * p5;   // 0..1279
        const float bias = bih[j] + bhh[j];
        float acc[8];
#pragma unroll
        for (int rr = 0; rr < 8; ++rr) acc[rr] = bias;
        const float4* w4 = (const float4*)(Wih + (size_t)j * HH);
#pragma unroll 4
        for (int k4 = 0; k4 < HH / 4; ++k4) {
            const float4 wv = w4[k4];
#pragma unroll
            for (int rr = 0; rr < 8; ++rr) {
                const float4 xv = ((const float4*)&xs[rr][0])[k4];
                acc[rr] += wv.x * xv.x + wv.y * xv.y + wv.z * xv.z + wv.w * xv.w;
            }
        }
        const int q = j / HH;
        const int hi = j - q * HH;
        const int pp = hi / UPB;
        const int uu = hi - pp * UPB;
        const int ug = uu >> 2, u4 = uu & 3;
        float* dst = Gp + ((((size_t)t * NBLK + pp) * 4 + q) * 10 + ug) * 128 + u4;
#pragma unroll
        for (int rr = 0; rr < 8; ++rr) dst[(b0 + rr) * 4] = acc[rr];
    }
}

// ---------------- Wout fp32 -> bf16 ----------------
__global__ __launch_bounds__(256) void wcvt(const float* __restrict__ src,
                                            unsigned short* __restrict__ dst, int n4) {
    const int i = blockIdx.x * 256 + threadIdx.x;
    if (i < n4) {
        const float4 v = ((const float4*)src)[i];
        ushort4 o;
        o.x = f2bf(v.x); o.y = f2bf(v.y); o.z = f2bf(v.z); o.w = f2bf(v.w);
        ((ushort4*)dst)[i] = o;
    }
}

// ---------------- Stage C: batched MFMA recurrence, 8 blocks ----------------
// Block p owns hidden units [p*40,p*40+40) (160 gate rows) for ALL 32 batches.
// Wave w (10 waves) owns n-tile w (16 gate rows): 10 B-frags/lane = 40 VGPR,
// kept resident via per-iteration keep-alive asm (small enough not to spill).
// Each wave computes both m-tiles (batches 0-15, 16-31): 20 MFMAs/step.
// Flags: done[0..7] in ONE cacheline; poll = single coalesced 32B read/wave
// with s_sleep backoff; signal = one plain atomic store per block.
__global__ __launch_bounds__(RTHR, 3) void stage_rec(const float* __restrict__ Gp,
                                                     const float* __restrict__ Whh,
                                                     unsigned short* __restrict__ Hsb,
                                                     unsigned short* __restrict__ hb,  // [2][BB][HH] bf16
                                                     int* __restrict__ done) {         // [8] one line
    const int p = blockIdx.x;             // 0..7
    const int tid = threadIdx.x;
    const int l = tid & 63, w = tid >> 6; // wave = n-tile 0..9
    const int lr = l & 15, lk = l >> 4;

    __shared__ float Gl[BB * GLP];        // 20.6 KB (only LDS)

    // ---- one-time: 10 B fragments (n-tile w) into VGPRs ----
    bf16x8v bfr[10];
    {
        const int r0 = w * 16 + lr;                        // slice gate-row 0..159
        const int j0 = (r0 / UPB) * HH + p * UPB + (r0 % UPB);
        const float* s0 = Whh + (size_t)j0 * HH + lk * 8;
#pragma unroll
        for (int kc = 0; kc < 10; ++kc) {
            union { unsigned short s[8]; bf16x8v v; } u;
#pragma unroll
            for (int e = 0; e < 8; ++e) u.s[e] = f2bf(s0[kc * 32 + e]);
            bfr[kc] = u.v;
        }
    }

    const int mc = tid & 31;              // batch for cell update
    const int gidx = tid >> 5;            // unit-group; cell phase uses gidx<10
    const int uc0 = gidx * 4;             // 4 adjacent units
    float c0 = 0.f, c1 = 0.f, c2 = 0.f, c3 = 0.f;

    for (int t = 0; t < TT; ++t) {
        // keep-alive: B-frags are "modified" each iter -> cannot be rematerialized
#pragma unroll
        for (int kc = 0; kc < 10; ++kc) asm volatile("" : "+v"(bfr[kc]));

        // gate-input prefetch: one float4 per q (coalesced across mc)
        float4 g[4];
        if (gidx < 10) {
            const size_t gbase = ((size_t)t * NBLK + p) * 4;
#pragma unroll
            for (int q = 0; q < 4; ++q)
                g[q] = ((const float4*)Gp)[(gbase + q) * 320 + (size_t)gidx * 32 + mc];
        }
        if (t > 0) {
            // poll: lanes 0-7 read the single flag line (one coalesced txn/wave)
            int ok;
            do {
                int v = 0x7fffffff;
                if (l < NBLK)
                    v = __hip_atomic_load(&done[l], __ATOMIC_RELAXED, __HIP_MEMORY_SCOPE_AGENT);
                ok = __all(v >= t);
                if (!ok) __builtin_amdgcn_s_sleep(1);
            } while (!ok);
            asm volatile("" ::: "memory");   // h loads below stay below

            // A fragments from coherence point; both m-tiles for this wave
            const unsigned long long* a0 = (const unsigned long long*)
                (hb + ((size_t)(t & 1) * BB + lr) * HH + lk * 8);
            const unsigned long long* a1 = (const unsigned long long*)
                (hb + ((size_t)(t & 1) * BB + 16 + lr) * HH + lk * 8);
            f32x4 acc0 = {}, acc1 = {};
#pragma unroll
            for (int kc = 0; kc < 10; ++kc) {
                union { unsigned long long q[2]; bf16x8v v; } ua, ub;
                ua.q[0] = __hip_atomic_load(a0 + (size_t)kc * 8,
                                            __ATOMIC_RELAXED, __HIP_MEMORY_SCOPE_AGENT);
                ua.q[1] = __hip_atomic_load(a0 + (size_t)kc * 8 + 1,
                                            __ATOMIC_RELAXED, __HIP_MEMORY_SCOPE_AGENT);
                ub.q[0] = __hip_atomic_load(a1 + (size_t)kc * 8,
                                            __ATOMIC_RELAXED, __HIP_MEMORY_SCOPE_AGENT);
                ub.q[1] = __hip_atomic_load(a1 + (size_t)kc * 8 + 1,
                                            __ATOMIC_RELAXED, __HIP_MEMORY_SCOPE_AGENT);
                acc0 = __builtin_amdgcn_mfma_f32_16x16x32_bf16(ua.v, bfr[kc], acc0, 0, 0, 0);
                acc1 = __builtin_amdgcn_mfma_f32_16x16x32_bf16(ub.v, bfr[kc], acc1, 0, 0, 0);
            }
#pragma unroll
            for (int rg = 0; rg < 4; ++rg) {
                // C/D: row=(lane>>4)*4+reg (m), col=lane&15 (n)
                Gl[(lk * 4 + rg) * GLP + w * 16 + lr] = acc0[rg];
                Gl[(16 + lk * 4 + rg) * GLP + w * 16 + lr] = acc1[rg];
            }
        }
        __syncthreads();   // Gl ready

        if (gidx < 10) {
            float a[4][4];
#pragma unroll
            for (int q = 0; q < 4; ++q) {
                const float* gl = &Gl[mc * GLP + q * UPB + uc0];
                a[q][0] = g[q].x + (t > 0 ? gl[0] : 0.f);
                a[q][1] = g[q].y + (t > 0 ? gl[1] : 0.f);
                a[q][2] = g[q].z + (t > 0 ? gl[2] : 0.f);
                a[q][3] = g[q].w + (t > 0 ? gl[3] : 0.f);
            }
            const float n0 = fsigm(a[1][0]) * c0 + fsigm(a[0][0]) * ftanh(a[2][0]);
            const float n1 = fsigm(a[1][1]) * c1 + fsigm(a[0][1]) * ftanh(a[2][1]);
            const float n2 = fsigm(a[1][2]) * c2 + fsigm(a[0][2]) * ftanh(a[2][2]);
            const float n3 = fsigm(a[1][3]) * c3 + fsigm(a[0][3]) * ftanh(a[2][3]);
            const float h0 = fsigm(a[3][0]) * ftanh(n0);
            const float h1 = fsigm(a[3][1]) * ftanh(n1);
            const float h2 = fsigm(a[3][2]) * ftanh(n2);
            const float h3 = fsigm(a[3][3]) * ftanh(n3);
            c0 = n0; c1 = n1; c2 = n2; c3 = n3;
            const unsigned long long hpk =
                (unsigned long long)f2bf(h0) |
                ((unsigned long long)f2bf(h1) << 16) |
                ((unsigned long long)f2bf(h2) << 32) |
                ((unsigned long long)f2bf(h3) << 48);
            *(unsigned long long*)(Hsb + ((size_t)mc * TT + t) * HH + p * UPB + uc0) = hpk;
            __hip_atomic_store((unsigned long long*)(hb + ((size_t)((t + 1) & 1) * BB + mc) * HH + p * UPB + uc0),
                               hpk, __ATOMIC_RELAXED, __HIP_MEMORY_SCOPE_AGENT);
        }
        __syncthreads();   // per-wave vmcnt(0) drain: publishes at coherence point
        if (tid == 0)
            __hip_atomic_store(&done[p], t + 1, __ATOMIC_RELAXED, __HIP_MEMORY_SCOPE_AGENT);
    }
}

// ---------------- Stage D: MFMA bf16 GEMM: out[m][v] = Hsb[m,:] . Woutb[v,:] + bout[v] ----------------
__global__ __launch_bounds__(256, 2) void stage_logits_mfma(const unsigned short* __restrict__ A,
                                                            const unsigned short* __restrict__ Bm,
                                                            const float* __restrict__ bout,
                                                            float* __restrict__ out) {
    __shared__ unsigned short As[128][40];
    __shared__ unsigned short Bs[128][40];
    const int tid = threadIdx.x;
    const int m0 = blockIdx.y * 128;
    const int n0 = blockIdx.x * 128;
    const int w = tid >> 6, l = tid & 63;
    const int wr = w >> 1, wc = w & 1;
    const int lr = l & 15, lk = l >> 4;

    f32x4 acc[4][4] = {};
    for (int k0 = 0; k0 < HH; k0 += 32) {
#pragma unroll
        for (int i = 0; i < 2; ++i) {
            const int uidx = tid + 256 * i;
            const int rr = uidx >> 2, ss = uidx & 3;
            *(uint4*)&As[rr][ss * 8] = *(const uint4*)(A + (size_t)(m0 + rr) * HH + k0 + ss * 8);
            *(uint4*)&Bs[rr][ss * 8] = *(const uint4*)(Bm + (size_t)(n0 + rr) * HH + k0 + ss * 8);
        }
        __syncthreads();
        bf16x8v af[4], bfr[4];
#pragma unroll
        for (int f = 0; f < 4; ++f) {
            af[f]  = *(const bf16x8v*)&As[wr * 64 + f * 16 + lr][lk * 8];
            bfr[f] = *(const bf16x8v*)&Bs[wc * 64 + f * 16 + lr][lk * 8];
        }
#pragma unroll
        for (int fm = 0; fm < 4; ++fm)
#pragma unroll
            for (int fn = 0; fn < 4; ++fn)
                acc[fm][fn] = __builtin_amdgcn_mfma_f32_16x16x32_bf16(af[fm], bfr[fn], acc[fm][fn], 0, 0, 0);
        __syncthreads();
    }
#pragma unroll
    for (int fn = 0; fn < 4; ++fn) {
        const int n = n0 + wc * 64 + fn * 16 + lr;
        const float bv = bout[n];
#pragma unroll
        for (int fm = 0; fm < 4; ++fm) {
            const int mbase = m0 + wr * 64 + fm * 16 + lk * 4;
#pragma unroll
            for (int rg = 0; rg < 4; ++rg)
                out[(size_t)(mbase + rg) * VV + n] = acc[fm][fn][rg] + bv;
        }
    }
}

// ---------------- Stage E: in-place log_softmax over V per row ----------------
__global__ __launch_bounds__(256) void stage_lsm(float* __restrict__ out) {
    __shared__ float buf[VV];
    __shared__ float red[16];
    const size_t m = blockIdx.x;
    float4* row4 = (float4*)(out + m * VV);
    float4* buf4 = (float4*)buf;
    const int tid = threadIdx.x;

    float mx = -INFINITY;
    for (int k4 = tid; k4 < VV / 4; k4 += 256) {
        const float4 v = row4[k4];
        buf4[k4] = v;
        mx = fmaxf(mx, fmaxf(fmaxf(v.x, v.y), fmaxf(v.z, v.w)));
    }
#pragma unroll
    for (int off = 32; off > 0; off >>= 1) mx = fmaxf(mx, __shfl_down(mx, off, 64));
    if ((tid & 63) == 0) red[tid >> 6] = mx;
    __syncthreads();
    if (tid == 0) {
        float m2 = red[0];
        for (int i = 1; i < 4; ++i) m2 = fmaxf(m2, red[i]);
        red[0] = m2;
    }
    __syncthreads();
    mx = red[0];

    float s = 0.f;
    for (int k4 = tid; k4 < VV / 4; k4 += 256) {
        const float4 v = buf4[k4];
        s += __expf(v.x - mx) + __expf(v.y - mx) + __expf(v.z - mx) + __expf(v.w - mx);
    }
#pragma unroll
    for (int off = 32; off > 0; off >>= 1) s += __shfl_down(s, off, 64);
    if ((tid & 63) == 0) red[8 + (tid >> 6)] = s;
    __syncthreads();
    if (tid == 0) {
        float s2 = 0.f;
        for (int i = 0; i < 4; ++i) s2 += red[8 + i];
        red[8] = logf(s2);
    }
    __syncthreads();
    const float lse = mx + red[8];
    for (int k4 = tid; k4 < VV / 4; k4 += 256) {
        float4 v = buf4[k4];
        v.x -= lse; v.y -= lse; v.z -= lse; v.w -= lse;
        row4[k4] = v;
    }
}

extern "C" void kernel_launch(void* const* d_in, const int* in_sizes, int n_in,
                              void* d_out, int out_size, void* d_ws, size_t ws_size,
                              hipStream_t stream) {
    const float* ac   = (const float*)d_in[0];
    const int*   tok  = (const int*)d_in[1];
    const float* emb  = (const float*)d_in[2];
    const float* Win  = (const float*)d_in[3];
    const float* bin  = (const float*)d_in[4];
    const float* Wih  = (const float*)d_in[5];
    const float* Whh  = (const float*)d_in[6];
    const float* bih  = (const float*)d_in[7];
    const float* bhh  = (const float*)d_in[8];
    const float* Wout = (const float*)d_in[9];
    const float* bout = (const float*)d_in[10];
    float* out = (float*)d_out;

    float* X  = (float*)d_ws;                                   // [T*B,H] fp32, 21 MB
    float* Gp = X + (size_t)TT * BB * HH;                       // [T][8][4][10][32][4], 84 MB
    unsigned short* Hsb   = (unsigned short*)(Gp + (size_t)TT * BB * G4);  // [B][T][H] bf16
    unsigned short* Woutb = Hsb + (size_t)TT * BB * HH;         // [V][H] bf16
    unsigned short* hb    = Woutb + (size_t)VV * HH;            // [2][BB][HH] bf16 (atomics only)
    int* done = (int*)(hb + 2 * BB * HH);                       // [8] one cacheline

    stage_x<<<dim3(TT * BB / 8), dim3(320), 0, stream>>>(ac, tok, emb, Win, bin, X);
    stage_gin<<<dim3(TT * BB / 8), dim3(256), 0, stream>>>(X, Wih, bih, bhh, Gp);
    wcvt<<<dim3((VV * HH / 4 + 255) / 256), dim3(256), 0, stream>>>(Wout, Woutb, VV * HH / 4);
    hipMemsetAsync(done, 0, NBLK * sizeof(int), stream);
    stage_rec<<<dim3(NBLK), dim3(RTHR), 0, stream>>>(Gp, Whh, Hsb, hb, done);
    stage_logits_mfma<<<dim3(VV / 128, TT * BB / 128), dim3(256), 0, stream>>>(Hsb, Woutb, bout, out);
    stage_lsm<<<dim3(TT * BB), dim3(256), 0, stream>>>(out);
}

// Round 11
// 5441.036 us; speedup vs baseline: 1.4952x; 1.4952x over previous
//
#include <hip/hip_runtime.h>
#include <hip/hip_bf16.h>

// Problem constants
#define BB 32     // batch
#define TT 512    // time
#define AA 512    // acoustic dim
#define EE 256    // emb dim
#define HH 320    // hidden
#define VV 8192   // vocab
#define KIN 768   // A+E
#define G4 1280   // 4*H

#define NBLK 8    // recurrence blocks (one sync group)
#define UPB 40    // hidden units per block
#define RPB 160   // gate rows per block
#define RTHR 640  // threads (10 waves)
#define WPAD 328  // padded bf16 row length
#define GLP 161   // gates LDS row pad
#define NCONS 160 // consumer blocks
#define NJOBS 8192

typedef __bf16 bf16x8v __attribute__((ext_vector_type(8)));
typedef float f32x4 __attribute__((ext_vector_type(4)));
typedef unsigned long long u64;

__device__ __forceinline__ float fsigm(float x) { return 1.f / (1.f + __expf(-x)); }
__device__ __forceinline__ float ftanh(float x) { return 2.f / (1.f + __expf(-2.f * x)) - 1.f; }
__device__ __forceinline__ unsigned short f2bf(float f) {
    __hip_bfloat16 h = __float2bfloat16(f);
    return *(unsigned short*)&h;
}

// ---------------- Stage A ----------------
__global__ __launch_bounds__(320) void stage_x(const float* __restrict__ ac,
                                               const int* __restrict__ tok,
                                               const float* __restrict__ emb,
                                               const float* __restrict__ Win,
                                               const float* __restrict__ bin,
                                               float* __restrict__ X) {
    __shared__ float xs[8][KIN];
    const int r0 = blockIdx.x * 8;
    const int tid = threadIdx.x;
    for (int rr = 0; rr < 8; ++rr) {
        const int r = r0 + rr;
        const int t = r >> 5;
        const int b = r & 31;
        const int tk = tok[b * TT + t];
        const float4* ac4  = (const float4*)(ac + ((size_t)b * TT + t) * AA);
        const float4* emb4 = (const float4*)(emb + (size_t)tk * EE);
        float4* xs4 = (float4*)&xs[rr][0];
        for (int k4 = tid; k4 < KIN / 4; k4 += 320) {
            float4 v;
            if (k4 < AA / 4) v = ac4[k4];
            else if (tk == 0) v = make_float4(0.f, 0.f, 0.f, 0.f);
            else v = emb4[k4 - AA / 4];
            xs4[k4] = v;
        }
    }
    __syncthreads();
    const int j = tid;
    float acc[8];
    const float bj = bin[j];
#pragma unroll
    for (int rr = 0; rr < 8; ++rr) acc[rr] = bj;
    const float4* w4 = (const float4*)(Win + (size_t)j * KIN);
#pragma unroll 4
    for (int k4 = 0; k4 < KIN / 4; ++k4) {
        const float4 wv = w4[k4];
#pragma unroll
        for (int rr = 0; rr < 8; ++rr) {
            const float4 xv = ((const float4*)&xs[rr][0])[k4];
            acc[rr] += wv.x * xv.x + wv.y * xv.y + wv.z * xv.z + wv.w * xv.w;
        }
    }
#pragma unroll
    for (int rr = 0; rr < 8; ++rr)
        X[(size_t)(r0 + rr) * HH + j] = tanhf(acc[rr]);
}

// ---------------- Stage B: Gp[(((t*8+p)*4+q)*40+u)*32 + b] ----------------
__global__ __launch_bounds__(256) void stage_gin(const float* __restrict__ X,
                                                 const float* __restrict__ Wih,
                                                 const float* __restrict__ bih,
                                                 const float* __restrict__ bhh,
                                                 float* __restrict__ Gp) {
    __shared__ float xs[8][HH];
    const int r0 = blockIdx.x * 8;
    const int tid = threadIdx.x;
    {
        const float4* src = (const float4*)(X + (size_t)r0 * HH);
        float4* dst = (float4*)&xs[0][0];
        for (int k4 = tid; k4 < 8 * HH / 4; k4 += 256) dst[k4] = src[k4];
    }
    __syncthreads();
    const int t = r0 >> 5;
    const int b0 = r0 & 31;
    for (int p5 = 0; p5 < 5; ++p5) {
        const int j = tid + 256 * p5;   // 0..1279
        const float bias = bih[j] + bhh[j];
        float acc[8];
#pragma unroll
        for (int rr = 0; rr < 8; ++rr) acc[rr] = bias;
        const float4* w4 = (const float4*)(Wih + (size_t)j * HH);
#pragma unroll 4
        for (int k4 = 0; k4 < HH / 4; ++k4) {
            const float4 wv = w4[k4];
#pragma unroll
            for (int rr = 0; rr < 8; ++rr) {
                const float4 xv = ((const float4*)&xs[rr][0])[k4];
                acc[rr] += wv.x * xv.x + wv.y * xv.y + wv.z * xv.z + wv.w * xv.w;
            }
        }
        const int q = j / HH;
        const int hi = j - q * HH;
        const int pp = hi / UPB;
        const int uu = hi - pp * UPB;
        float* dst = Gp + ((((size_t)t * NBLK + pp) * 4 + q) * UPB + uu) * BB + b0;
#pragma unroll
        for (int rr = 0; rr < 8; ++rr) dst[rr] = acc[rr];
    }
}

// ---------------- Wout fp32 -> bf16 ----------------
__global__ __launch_bounds__(256) void wcvt(const float* __restrict__ src,
                                            unsigned short* __restrict__ dst, int n4) {
    const int i = blockIdx.x * 256 + threadIdx.x;
    if (i < n4) {
        const float4 v = ((const float4*)src)[i];
        ushort4 o;
        o.x = f2bf(v.x); o.y = f2bf(v.y); o.z = f2bf(v.z); o.w = f2bf(v.w);
        ((ushort4*)dst)[i] = o;
    }
}

// ---------------- Stage C: rec producers (r5-proven) + logits consumers, one dispatch ----------------
// bid<64: bid&7==0 -> rec block p=bid>>3 (proven 4.06ms path, untouched math).
// bid>=64: consumer c=bid-64 computes 128x128 logits tiles ordered by t-chunk, gated on a
// shadow progress counter (cnt[32]) republished by rec block 0 (off the hot cnt line).
// Deadlock-free: 224 blocks x ~143KB LDS = 1 block/CU, all resident; rec never waits on consumers.
__global__ __launch_bounds__(RTHR) void stage_rec(const float* __restrict__ Gp,
                                                  const float* __restrict__ Whh,
                                                  unsigned short* __restrict__ Hsb,
                                                  float* __restrict__ hbuf,   // [2][BB][HH] fp32
                                                  int* __restrict__ cnt,      // [0]=counter, [32]=shadow
                                                  const unsigned short* __restrict__ Woutb,
                                                  const float* __restrict__ bout,
                                                  float* __restrict__ out) {
    __shared__ uint4 ldsbuf4[146560 / 16];
    char* ldsbuf = (char*)ldsbuf4;
    const int bid = blockIdx.x;
    const int tid = threadIdx.x;

    if (bid < 64) {
        if (bid & 7) return;              // ghosts
        const int p = bid >> 3;           // 0..7
        const int l = tid & 63, w = tid >> 6;
        const int lr = l & 15, lk = l >> 4;

        unsigned short (*Wl)[WPAD] = (unsigned short (*)[WPAD])ldsbuf;            // 104960 B
        unsigned short (*Hl)[WPAD] = (unsigned short (*)[WPAD])(ldsbuf + 104960); //  20992 B
        float* Gl = (float*)(ldsbuf + 125952);                                    //  20608 B

        // one-time: Whh slice -> bf16 LDS
        for (int idx = tid; idx < RPB * 40; idx += RTHR) {
            const int rr = idx / 40, s = idx - (idx / 40) * 40;
            const int q = rr / UPB, u = rr - (rr / UPB) * UPB;
            const float* src = Whh + (size_t)(q * HH + p * UPB + u) * HH + s * 8;
            const float4 v0 = *(const float4*)src;
            const float4 v1 = *(const float4*)(src + 4);
            unsigned short tmp[8] = { f2bf(v0.x), f2bf(v0.y), f2bf(v0.z), f2bf(v0.w),
                                      f2bf(v1.x), f2bf(v1.y), f2bf(v1.z), f2bf(v1.w) };
            *(uint4*)&Wl[rr][s * 8] = *(const uint4*)tmp;
        }
        __syncthreads();

        const int mc = tid & 31;
        const int uc0 = tid >> 5;             // 0..19
        const int uc1 = uc0 + 20;
        float c0 = 0.f, c1 = 0.f;
        const int mw = w & 1;
        const int np = w >> 1;

        for (int t = 0; t < TT; ++t) {
            const size_t gbase = ((size_t)t * NBLK + p) * 4;
            float g0[4], g1[4];
#pragma unroll
            for (int q = 0; q < 4; ++q) {
                g0[q] = Gp[((gbase + q) * UPB + uc0) * BB + mc];
                g1[q] = Gp[((gbase + q) * UPB + uc1) * BB + mc];
            }
            if (t > 0) {
                if (tid == 0) {
                    while (__hip_atomic_load(cnt, __ATOMIC_RELAXED, __HIP_MEMORY_SCOPE_AGENT) < NBLK * t)
                        __builtin_amdgcn_s_sleep(1);
                    __threadfence();          // acquire
                    if (p == 0)               // republish progress for consumers (rows < t ready)
                        __hip_atomic_store(&cnt[32], t, __ATOMIC_RELAXED, __HIP_MEMORY_SCOPE_AGENT);
                }
                __syncthreads();
                {
                    const int m = tid / 20, k0 = (tid - (tid / 20) * 20) * 16;
                    const float4* src = (const float4*)(hbuf + ((size_t)(t & 1) * BB + m) * HH + k0);
                    const float4 a = src[0], b2 = src[1], c2 = src[2], d2 = src[3];
                    unsigned short tmp[16] = {
                        f2bf(a.x), f2bf(a.y), f2bf(a.z), f2bf(a.w),
                        f2bf(b2.x), f2bf(b2.y), f2bf(b2.z), f2bf(b2.w),
                        f2bf(c2.x), f2bf(c2.y), f2bf(c2.z), f2bf(c2.w),
                        f2bf(d2.x), f2bf(d2.y), f2bf(d2.z), f2bf(d2.w) };
                    *(uint4*)&Hl[m][k0] = *(const uint4*)tmp;
                    *(uint4*)&Hl[m][k0 + 8] = *(const uint4*)(tmp + 8);
                }
                __syncthreads();
                f32x4 acc0 = {}, acc1 = {};
#pragma unroll
                for (int kc = 0; kc < 10; ++kc) {
                    const bf16x8v av = *(const bf16x8v*)&Hl[mw * 16 + lr][kc * 32 + lk * 8];
                    const bf16x8v b0 = *(const bf16x8v*)&Wl[np * 32 + lr][kc * 32 + lk * 8];
                    const bf16x8v b1 = *(const bf16x8v*)&Wl[np * 32 + 16 + lr][kc * 32 + lk * 8];
                    acc0 = __builtin_amdgcn_mfma_f32_16x16x32_bf16(av, b0, acc0, 0, 0, 0);
                    acc1 = __builtin_amdgcn_mfma_f32_16x16x32_bf16(av, b1, acc1, 0, 0, 0);
                }
#pragma unroll
                for (int rg = 0; rg < 4; ++rg) {
                    const int m = mw * 16 + lk * 4 + rg;
                    Gl[m * GLP + np * 32 + lr] = acc0[rg];
                    Gl[m * GLP + np * 32 + 16 + lr] = acc1[rg];
                }
                __syncthreads();
            }
            {
                float a0[4], a1[4];
#pragma unroll
                for (int q = 0; q < 4; ++q) {
                    a0[q] = g0[q] + (t > 0 ? Gl[mc * GLP + q * UPB + uc0] : 0.f);
                    a1[q] = g1[q] + (t > 0 ? Gl[mc * GLP + q * UPB + uc1] : 0.f);
                }
                const float cn0 = fsigm(a0[1]) * c0 + fsigm(a0[0]) * ftanh(a0[2]);
                const float hn0 = fsigm(a0[3]) * ftanh(cn0);
                const float cn1 = fsigm(a1[1]) * c1 + fsigm(a1[0]) * ftanh(a1[2]);
                const float hn1 = fsigm(a1[3]) * ftanh(cn1);
                c0 = cn0; c1 = cn1;
                Hsb[((size_t)mc * TT + t) * HH + p * UPB + uc0] = f2bf(hn0);
                Hsb[((size_t)mc * TT + t) * HH + p * UPB + uc1] = f2bf(hn1);
                float* hb = hbuf + ((size_t)((t + 1) & 1) * BB + mc) * HH + p * UPB;
                hb[uc0] = hn0;
                hb[uc1] = hn1;
            }
            __syncthreads();   // drains vmcnt: stores in L2
            if (tid == 0) {
                __threadfence();   // release: L2 writeback -> MALL (also makes Hsb consumer-visible)
                __hip_atomic_fetch_add(cnt, 1, __ATOMIC_RELAXED, __HIP_MEMORY_SCOPE_AGENT);
            }
        }
        // terminal: block 0 publishes full completion for consumers
        if (p == 0 && tid == 0) {
            while (__hip_atomic_load(cnt, __ATOMIC_RELAXED, __HIP_MEMORY_SCOPE_AGENT) < NBLK * TT)
                __builtin_amdgcn_s_sleep(1);
            __threadfence();
            __hip_atomic_store(&cnt[32], TT, __ATOMIC_RELAXED, __HIP_MEMORY_SCOPE_AGENT);
        }
    } else {
        // -------- consumer: logits tiles gated on shadow progress --------
        const int c = bid - 64;
        unsigned short (*As)[40] = (unsigned short (*)[40])ldsbuf;
        unsigned short (*Bs)[40] = (unsigned short (*)[40])(ldsbuf + 10240);
        const int l = tid & 63;
        const int w4v = tid >> 6;             // waves 0..9; GEMM uses 0..3
        const int wr = (w4v >> 1) & 1, wc = w4v & 1;
        const int lr = l & 15, lk = l >> 4;
        __shared__ int ready;

        for (int j = c; j < NJOBS; j += NCONS) {
            const int tc = j >> 11;           // t-chunk 0..3
            const int idx = j & 2047;
            const int nt = idx & 63;
            const int bidx = idx >> 6;        // 0..31
            const int need = (tc + 1) * 128;  // rows < need required
            if (tid == 0) {
                while (__hip_atomic_load(&cnt[32], __ATOMIC_RELAXED, __HIP_MEMORY_SCOPE_AGENT) < need)
                    __builtin_amdgcn_s_sleep(8);
                ready = 1;
            }
            __syncthreads();
            asm volatile("" ::: "memory");

            const int m0 = bidx * TT + tc * 128;
            const int n0 = nt * 128;
            f32x4 acc[4][4] = {};
            for (int k0 = 0; k0 < HH; k0 += 32) {
                if (tid < 512) {
                    const int rr = tid >> 2, ss = tid & 3;
                    *(uint4*)&As[rr][ss * 8] = *(const uint4*)(Hsb + (size_t)(m0 + rr) * HH + k0 + ss * 8);
                    *(uint4*)&Bs[rr][ss * 8] = *(const uint4*)(Woutb + (size_t)(n0 + rr) * HH + k0 + ss * 8);
                }
                __syncthreads();
                if (tid < 256) {
                    bf16x8v af[4], bfr[4];
#pragma unroll
                    for (int f = 0; f < 4; ++f) {
                        af[f]  = *(const bf16x8v*)&As[wr * 64 + f * 16 + lr][lk * 8];
                        bfr[f] = *(const bf16x8v*)&Bs[wc * 64 + f * 16 + lr][lk * 8];
                    }
#pragma unroll
                    for (int fm = 0; fm < 4; ++fm)
#pragma unroll
                        for (int fn = 0; fn < 4; ++fn)
                            acc[fm][fn] = __builtin_amdgcn_mfma_f32_16x16x32_bf16(af[fm], bfr[fn], acc[fm][fn], 0, 0, 0);
                }
                __syncthreads();
            }
            if (tid < 256) {
#pragma unroll
                for (int fn = 0; fn < 4; ++fn) {
                    const int n = n0 + wc * 64 + fn * 16 + lr;
                    const float bv = bout[n];
#pragma unroll
                    for (int fm = 0; fm < 4; ++fm) {
                        const int mbase = m0 + wr * 64 + fm * 16 + lk * 4;
#pragma unroll
                        for (int rg = 0; rg < 4; ++rg)
                            out[(size_t)(mbase + rg) * VV + n] = acc[fm][fn][rg] + bv;
                    }
                }
            }
        }
    }
}

// ---------------- Stage E: in-place log_softmax over V per row ----------------
__global__ __launch_bounds__(256) void stage_lsm(float* __restrict__ out) {
    __shared__ float buf[VV];
    __shared__ float red[16];
    const size_t m = blockIdx.x;
    float4* row4 = (float4*)(out + m * VV);
    float4* buf4 = (float4*)buf;
    const int tid = threadIdx.x;

    float mx = -INFINITY;
    for (int k4 = tid; k4 < VV / 4; k4 += 256) {
        const float4 v = row4[k4];
        buf4[k4] = v;
        mx = fmaxf(mx, fmaxf(fmaxf(v.x, v.y), fmaxf(v.z, v.w)));
    }
#pragma unroll
    for (int off = 32; off > 0; off >>= 1) mx = fmaxf(mx, __shfl_down(mx, off, 64));
    if ((tid & 63) == 0) red[tid >> 6] = mx;
    __syncthreads();
    if (tid == 0) {
        float m2 = red[0];
        for (int i = 1; i < 4; ++i) m2 = fmaxf(m2, red[i]);
        red[0] = m2;
    }
    __syncthreads();
    mx = red[0];

    float s = 0.f;
    for (int k4 = tid; k4 < VV / 4; k4 += 256) {
        const float4 v = buf4[k4];
        s += __expf(v.x - mx) + __expf(v.y - mx) + __expf(v.z - mx) + __expf(v.w - mx);
    }
#pragma unroll
    for (int off = 32; off > 0; off >>= 1) s += __shfl_down(s, off, 64);
    if ((tid & 63) == 0) red[8 + (tid >> 6)] = s;
    __syncthreads();
    if (tid == 0) {
        float s2 = 0.f;
        for (int i = 0; i < 4; ++i) s2 += red[8 + i];
        red[8] = logf(s2);
    }
    __syncthreads();
    const float lse = mx + red[8];
    for (int k4 = tid; k4 < VV / 4; k4 += 256) {
        float4 v = buf4[k4];
        v.x -= lse; v.y -= lse; v.z -= lse; v.w -= lse;
        row4[k4] = v;
    }
}

extern "C" void kernel_launch(void* const* d_in, const int* in_sizes, int n_in,
                              void* d_out, int out_size, void* d_ws, size_t ws_size,
                              hipStream_t stream) {
    const float* ac   = (const float*)d_in[0];
    const int*   tok  = (const int*)d_in[1];
    const float* emb  = (const float*)d_in[2];
    const float* Win  = (const float*)d_in[3];
    const float* bin  = (const float*)d_in[4];
    const float* Wih  = (const float*)d_in[5];
    const float* Whh  = (const float*)d_in[6];
    const float* bih  = (const float*)d_in[7];
    const float* bhh  = (const float*)d_in[8];
    const float* Wout = (const float*)d_in[9];
    const float* bout = (const float*)d_in[10];
    float* out = (float*)d_out;

    float* X  = (float*)d_ws;                                   // [T*B,H] fp32, 21 MB
    float* Gp = X + (size_t)TT * BB * HH;                       // 84 MB
    unsigned short* Hsb   = (unsigned short*)(Gp + (size_t)TT * BB * G4);  // [B][T][H] bf16
    unsigned short* Woutb = Hsb + (size_t)TT * BB * HH;         // [V][H] bf16
    float* hbuf = (float*)(Woutb + (size_t)VV * HH);            // [2][BB][HH] fp32
    int*   cnt  = (int*)(hbuf + 2 * BB * HH);                   // [0]=counter, [32]=shadow

    stage_x<<<dim3(TT * BB / 8), dim3(320), 0, stream>>>(ac, tok, emb, Win, bin, X);
    stage_gin<<<dim3(TT * BB / 8), dim3(256), 0, stream>>>(X, Wih, bih, bhh, Gp);
    wcvt<<<dim3((VV * HH / 4 + 255) / 256), dim3(256), 0, stream>>>(Wout, Woutb, VV * HH / 4);
    hipMemsetAsync(cnt, 0, 256, stream);
    stage_rec<<<dim3(64 + NCONS), dim3(RTHR), 0, stream>>>(Gp, Whh, Hsb, hbuf, cnt,
                                                           Woutb, bout, out);
    stage_lsm<<<dim3(TT * BB), dim3(256), 0, stream>>>(out);
}